// Round 22
// baseline (963.663 us; speedup 1.0000x reference)
//
#include <hip/hip_runtime.h>
#include <hip/hip_bf16.h>

constexpr int cB = 32, cN = 64, cL = 64, cT = 10, cD = 256, cH = 512, cH3 = 1536;
constexpr int cBN = cB * cN;   // 2048
constexpr int cNP1 = cN + 1;   // 65: hidden tape, slot 0 = h0, slot n+1 = hs[:,n,:]

typedef __bf16 bf16x8 __attribute__((ext_vector_type(8)));
typedef float f32x4 __attribute__((ext_vector_type(4)));
typedef _Float16 h2t __attribute__((ext_vector_type(2)));

__device__ __forceinline__ ushort f2bf(float f) {
  __hip_bfloat16 h = __float2bfloat16(f);
  return *reinterpret_cast<ushort*>(&h);
}

// pack two f32 -> two f16 in one uint (v_cvt_pkrtz_f16_f32)
__device__ __forceinline__ unsigned pkh2(float a, float b) {
  auto p = __builtin_amdgcn_cvt_pkrtz(a, b);   // __fp16 ext_vector(2)
  return __builtin_bit_cast(unsigned, p);
}

// f16-pair dot with f32 accumulator
__device__ __forceinline__ float fdot2u(unsigned w, unsigned h, float acc) {
#if __has_builtin(__builtin_amdgcn_fdot2)
  return __builtin_amdgcn_fdot2(__builtin_bit_cast(h2t, w),
                                __builtin_bit_cast(h2t, h), acc, false);
#else
  h2t a = __builtin_bit_cast(h2t, w), b = __builtin_bit_cast(h2t, h);
  return acc + (float)a[0] * (float)b[0] + (float)a[1] * (float)b[1];
#endif
}

// ---------------- xb[bn][d] = bf16( sum_l emb[sents[bn][l]][d] ) ----------------
__global__ void k_embed_x(const int* __restrict__ sents, const float* __restrict__ emb,
                          ushort* __restrict__ xb) {
  __shared__ int idx[cL];
  int bn = blockIdx.x, t = threadIdx.x;
  if (t < cL) idx[t] = sents[bn * cL + t];
  __syncthreads();
  float acc = 0.f;
#pragma unroll 8
  for (int l = 0; l < cL; ++l) acc += emb[(long)idx[l] * cD + t];
  xb[bn * cD + t] = f2bf(acc);
}

// ---------------- tsum[b][d] = sum_t emb[titles[b][0][t]][d] ----------------
__global__ void k_title(const int* __restrict__ titles, const float* __restrict__ emb,
                        float* __restrict__ tsum) {
  __shared__ int idx[cT];
  int b = blockIdx.x, t = threadIdx.x;
  if (t < cT) idx[t] = titles[b * cN * cT + t];
  __syncthreads();
  float acc = 0.f;
#pragma unroll
  for (int i = 0; i < cT; ++i) acc += emb[(long)idx[i] * cD + t];
  tsum[b * cD + t] = acc;
}

// ---------------- h0 = tsum @ Wt + bt -> hse slot 0 ----------------
__global__ void k_h0(const float* __restrict__ tsum, const float* __restrict__ Wt,
                     const float* __restrict__ bt, float* __restrict__ hse) {
  int i = blockIdx.x * blockDim.x + threadIdx.x;  // B*H
  int b = i >> 9, hh = i & (cH - 1);
  const float* ts = tsum + b * cD;
  float acc = bt[hh];
  for (int k = 0; k < cD; ++k) acc += ts[k] * Wt[(long)k * cH + hh];
  hse[(long)b * cNP1 * cH + hh] = acc;
}

// ---------------- W_ih -> transposed bf16: bti[col][k] ----------------
__global__ void k_bti(const float* __restrict__ W, ushort* __restrict__ Bt) {
  __shared__ float tile[64][65];
  int col0 = blockIdx.x * 64, k0 = blockIdx.y * 64;
  int t = threadIdx.x;
  for (int i = t; i < 4096; i += 256) {
    int kr = i >> 6, cc = i & 63;
    tile[kr][cc] = W[(long)(k0 + kr) * cH3 + col0 + cc];
  }
  __syncthreads();
  for (int i = t; i < 4096; i += 256) {
    int cc = i >> 6, kr = i & 63;
    Bt[(long)(col0 + cc) * cD + k0 + kr] = f2bf(tile[kr][cc]);
  }
}

// ---------------- W_att_in -> transposed bf16: bq[col][k] ----------------
__global__ void k_bq(const float* __restrict__ W, ushort* __restrict__ Bt) {
  __shared__ float tile[64][65];
  int col0 = blockIdx.x * 64, k0 = blockIdx.y * 64;
  int t = threadIdx.x;
  for (int i = t; i < 4096; i += 256) {
    int kr = i >> 6, cc = i & 63;
    tile[kr][cc] = W[(long)(k0 + kr) * cH + col0 + cc];
  }
  __syncthreads();
  for (int i = t; i < 4096; i += 256) {
    int cc = i >> 6, kr = i & 63;
    Bt[(long)(col0 + cc) * cH + k0 + kr] = f2bf(tile[kr][cc]);
  }
}

// ---------------- W_hh -> f16-pair packed: Wp[(g*64+k8)*512 + c] = 8 halves ----------------
// grid (64 k8, 6 cg); block 256
__global__ void k_wpack(const float* __restrict__ W, uint4* __restrict__ Wp) {
  int k8 = blockIdx.x, cg = blockIdx.y;
  int t = threadIdx.x;
  int cglob = cg * 256 + t;          // 0..1535
  int g = cglob >> 9, c = cglob & 511;
  float v[8];
#pragma unroll
  for (int j = 0; j < 8; ++j) v[j] = W[(long)(k8 * 8 + j) * cH3 + cglob];
  Wp[(g * 64 + k8) * 512 + c] = make_uint4(pkh2(v[0], v[1]), pkh2(v[2], v[3]),
                                           pkh2(v[4], v[5]), pkh2(v[6], v[7]));
}

// ---------------- GI = X @ W_ih + b_ih via MFMA ----------------
// grid (32 row-tiles, 24 col-tiles); block 256 (4 waves); tile 64x64, K=256 (4 chunks)
__global__ void __launch_bounds__(256) k_gi_mfma(
    const ushort* __restrict__ xb, const ushort* __restrict__ Bt,
    const float* __restrict__ b_ih, float* __restrict__ gi) {
  __shared__ char lds[16384];
  int bn0 = blockIdx.x * 64, col0 = blockIdx.y * 64;
  int t = threadIdx.x;
  int w = t >> 6, lane = t & 63;
  f32x4 acc[4];
#pragma unroll
  for (int i = 0; i < 4; ++i) acc[i] = (f32x4){0.f, 0.f, 0.f, 0.f};
  int r = lane & 15, kg = lane >> 4;
  for (int kc = 0; kc < 4; ++kc) {
    int k0 = kc * 64;
#pragma unroll
    for (int p = 0; p < 2; ++p) {
      int i = t + p * 256;
      int row = i >> 3, ks = i & 7;
      float4 va = *(const float4*)(xb + (long)(bn0 + row) * cD + k0 + ks * 8);
      *(float4*)(lds + ((row * 128 + ks * 16) ^ ((row & 7) << 4))) = va;
      float4 vb = *(const float4*)(Bt + (long)(col0 + row) * cD + k0 + ks * 8);
      *(float4*)(lds + 8192 + ((row * 128 + ks * 16) ^ ((row & 7) << 4))) = vb;
    }
    __syncthreads();
#pragma unroll
    for (int s = 0; s < 2; ++s) {
      int arow = w * 16 + r;
      bf16x8 a = *(const bf16x8*)(lds + ((arow * 128 + s * 64 + kg * 16) ^ ((arow & 7) << 4)));
#pragma unroll
      for (int cf = 0; cf < 4; ++cf) {
        int bcol = cf * 16 + r;
        bf16x8 bb = *(const bf16x8*)(lds + 8192 +
                                     ((bcol * 128 + s * 64 + kg * 16) ^ ((bcol & 7) << 4)));
        acc[cf] = __builtin_amdgcn_mfma_f32_16x16x32_bf16(a, bb, acc[cf], 0, 0, 0);
      }
    }
    __syncthreads();
  }
  int rq = lane >> 4;
#pragma unroll
  for (int cf = 0; cf < 4; ++cf) {
    int col = col0 + cf * 16 + r;
    float bv = b_ih[col];
#pragma unroll
    for (int reg = 0; reg < 4; ++reg) {
      int row = bn0 + w * 16 + rq * 4 + reg;
      gi[(long)row * cH3 + col] = acc[cf][reg] + bv;
    }
  }
}

// ---------------- one GRU step (v7: 1 thread = 1 output, full K, no reduction) ----------------
// grid 64 = bg(4: 8 batches) x cg(16: 32 cols); block 256
// t = b_l(t>>5: 8 batches) | cl(t&31: 32 cols)
__global__ void __launch_bounds__(256) k_gru_step(
    const float* __restrict__ gi, const uint4* __restrict__ Wp,
    const float* __restrict__ b_hh, float* __restrict__ hse, int step) {
  __shared__ uint4 hp4[8][64];   // 8 batches x 512 h as f16 pairs (8 KB)
  int cg = blockIdx.x & 15;
  int bg = blockIdx.x >> 4;
  int t = threadIdx.x;
  int b_l = t >> 5, cl = t & 31;
  int b = bg * 8 + b_l;
  int col = cg * 32 + cl;

  // prefetch epilogue operands (independent of the matmul)
  long girow = ((long)b * cN + step) * cH3;
  float ir = gi[girow + col];
  float iz = gi[girow + cH + col];
  float inn = gi[girow + 2 * cH + col];
  float bhr = b_hh[col], bhz = b_hh[col + cH], bhn = b_hh[col + 2 * cH];
  float hold = hse[((long)b * cNP1 + step) * cH + col];

  // stage 8 hidden rows as f16 pairs: 512 uint4, 2 per thread
#pragma unroll
  for (int p = 0; p < 2; ++p) {
    int j = t + p * 256;
    int sb = j >> 6, j8 = j & 63;
    const float* hrow = hse + ((long)(bg * 8 + sb) * cNP1 + step) * cH + j8 * 8;
    float4 v0 = *(const float4*)(hrow);
    float4 v1 = *(const float4*)(hrow + 4);
    hp4[sb][j8] = make_uint4(pkh2(v0.x, v0.y), pkh2(v0.z, v0.w),
                             pkh2(v1.x, v1.y), pkh2(v1.z, v1.w));
  }
  __syncthreads();

  float a0 = 0.f, a1 = 0.f, z0 = 0.f, z1 = 0.f, n0 = 0.f, n1 = 0.f;
  const uint4* wr0 = Wp + col;
  const uint4* wz0 = Wp + 64 * 512 + col;
  const uint4* wn0 = Wp + 128 * 512 + col;
#pragma unroll 8
  for (int k8 = 0; k8 < 64; ++k8) {
    uint4 hp = hp4[b_l][k8];          // 2-addr broadcast per wave (free)
    uint4 wr = wr0[k8 * 512];         // 512B contiguous per wave-half
    uint4 wz = wz0[k8 * 512];
    uint4 wn = wn0[k8 * 512];
    a0 = fdot2u(wr.x, hp.x, a0); a1 = fdot2u(wr.y, hp.y, a1);
    a0 = fdot2u(wr.z, hp.z, a0); a1 = fdot2u(wr.w, hp.w, a1);
    z0 = fdot2u(wz.x, hp.x, z0); z1 = fdot2u(wz.y, hp.y, z1);
    z0 = fdot2u(wz.z, hp.z, z0); z1 = fdot2u(wz.w, hp.w, z1);
    n0 = fdot2u(wn.x, hp.x, n0); n1 = fdot2u(wn.y, hp.y, n1);
    n0 = fdot2u(wn.z, hp.z, n0); n1 = fdot2u(wn.w, hp.w, n1);
  }
  float rr = 1.f / (1.f + __expf(-(ir + a0 + a1 + bhr)));
  float zz = 1.f / (1.f + __expf(-(iz + z0 + z1 + bhz)));
  float nn = tanhf(inn + rr * (n0 + n1 + bhn));
  hse[((long)b * cNP1 + step + 1) * cH + col] = (1.f - zz) * nn + zz * hold;
}

// ---------------- hs -> bf16: hsb[bn][k]  AND catb upper half ----------------
__global__ void k_hscast(const float* __restrict__ hse, ushort* __restrict__ hsb,
                         ushort* __restrict__ catb) {
  int bn = blockIdx.x, t = threadIdx.x;  // 128 threads x float4
  int b = bn >> 6, n = bn & 63;
  float4 v = ((const float4*)(hse + ((long)b * cNP1 + 1 + n) * cH))[t];
  ushort4 o;
  o.x = f2bf(v.x); o.y = f2bf(v.y); o.z = f2bf(v.z); o.w = f2bf(v.w);
  *(ushort4*)(hsb + (long)bn * cH + t * 4) = o;
  *(ushort4*)(catb + (long)bn * 1024 + 512 + t * 4) = o;
}

// ---------------- q = hs @ W_att_in via MFMA ----------------
// grid (32 row-tiles, 8 col-tiles); block 256 (4 waves); tile 64x64, K=512 (8 chunks)
__global__ void __launch_bounds__(256) k_q_mfma(
    const ushort* __restrict__ hsb, const ushort* __restrict__ Bt,
    float* __restrict__ q) {
  __shared__ char lds[16384];
  int bn0 = blockIdx.x * 64, col0 = blockIdx.y * 64;
  int t = threadIdx.x;
  int w = t >> 6, lane = t & 63;
  f32x4 acc[4];
#pragma unroll
  for (int i = 0; i < 4; ++i) acc[i] = (f32x4){0.f, 0.f, 0.f, 0.f};
  int r = lane & 15, kg = lane >> 4;
  for (int kc = 0; kc < 8; ++kc) {
    int k0 = kc * 64;
#pragma unroll
    for (int p = 0; p < 2; ++p) {
      int i = t + p * 256;
      int row = i >> 3, ks = i & 7;
      float4 va = *(const float4*)(hsb + (long)(bn0 + row) * cH + k0 + ks * 8);
      *(float4*)(lds + ((row * 128 + ks * 16) ^ ((row & 7) << 4))) = va;
      float4 vb = *(const float4*)(Bt + (long)(col0 + row) * cH + k0 + ks * 8);
      *(float4*)(lds + 8192 + ((row * 128 + ks * 16) ^ ((row & 7) << 4))) = vb;
    }
    __syncthreads();
#pragma unroll
    for (int s = 0; s < 2; ++s) {
      int arow = w * 16 + r;
      bf16x8 a = *(const bf16x8*)(lds + ((arow * 128 + s * 64 + kg * 16) ^ ((arow & 7) << 4)));
#pragma unroll
      for (int cf = 0; cf < 4; ++cf) {
        int bcol = cf * 16 + r;
        bf16x8 bb = *(const bf16x8*)(lds + 8192 +
                                     ((bcol * 128 + s * 64 + kg * 16) ^ ((bcol & 7) << 4)));
        acc[cf] = __builtin_amdgcn_mfma_f32_16x16x32_bf16(a, bb, acc[cf], 0, 0, 0);
      }
    }
    __syncthreads();
  }
  int rq = lane >> 4;
#pragma unroll
  for (int cf = 0; cf < 4; ++cf) {
    int col = col0 + cf * 16 + r;
#pragma unroll
    for (int reg = 0; reg < 4; ++reg) {
      int row = bn0 + w * 16 + rq * 4 + reg;
      q[(long)row * cH + col] = acc[cf][reg];
    }
  }
}

// ---------------- causal attention v2: 4 queries/block, key early-exit ----------------
// grid (32 b, 16 qg); block 256. Writes catb lower half (bf16 context).
__global__ void k_attn2(const float* __restrict__ q, const float* __restrict__ hse,
                        ushort* __restrict__ catb) {
  __shared__ float qs[4][cH];       // 8 KB
  __shared__ float part[256][5];    // stride 5: conflict-free (gcd(5,32)=1)
  __shared__ float aw[4][cN];
  int b = blockIdx.x, qg = blockIdx.y;
  int n0 = qg * 4;
  int kmax = n0 + 3;
  int t = threadIdx.x;
  for (int i = t; i < 4 * 128; i += 256) {
    int g = i >> 7, j = i & 127;
    ((float4*)qs[g])[j] = ((const float4*)(q + (long)(b * 64 + n0 + g) * cH))[j];
  }
  __syncthreads();
  int k = t & 63, p = t >> 6;
  float s0 = 0.f, s1 = 0.f, s2 = 0.f, s3 = 0.f;
  if (k <= kmax) {
    const float* hrow = hse + ((long)b * cNP1 + 1 + k) * cH + p * 128;
    const float* q0 = &qs[0][p * 128];
    const float* q1 = &qs[1][p * 128];
    const float* q2 = &qs[2][p * 128];
    const float* q3 = &qs[3][p * 128];
#pragma unroll 4
    for (int j = 0; j < 128; ++j) {
      float hv = hrow[j];
      s0 += q0[j] * hv;
      s1 += q1[j] * hv;
      s2 += q2[j] * hv;
      s3 += q3[j] * hv;
    }
  }
  part[t][0] = s0; part[t][1] = s1; part[t][2] = s2; part[t][3] = s3;
  __syncthreads();
  if (t < 64) {
#pragma unroll
    for (int g = 0; g < 4; ++g) {
      float sc = part[t][g] + part[t + 64][g] + part[t + 128][g] + part[t + 192][g];
      if (t > n0 + g) sc = -1e30f;  // causal (ref's log(1e-45) -> exp underflow)
      float m = sc;
#pragma unroll
      for (int off = 32; off; off >>= 1) m = fmaxf(m, __shfl_xor(m, off));
      float e = __expf(sc - m);
      float sum = e;
#pragma unroll
      for (int off = 32; off; off >>= 1) sum += __shfl_xor(sum, off);
      aw[g][t] = e / sum;
    }
  }
  __syncthreads();
  float c0[4] = {0, 0, 0, 0}, c1[4] = {0, 0, 0, 0};
  for (int kk = 0; kk <= kmax; ++kk) {
    const float* hr = hse + ((long)b * cNP1 + 1 + kk) * cH;
    float h0 = hr[t], h1 = hr[t + 256];
#pragma unroll
    for (int g = 0; g < 4; ++g) {
      float a = aw[g][kk];
      c0[g] += a * h0;
      c1[g] += a * h1;
    }
  }
#pragma unroll
  for (int g = 0; g < 4; ++g) {
    long row = (long)(b * 64 + n0 + g) * 1024;
    catb[row + t] = f2bf(c0[g]);
    catb[row + t + 256] = f2bf(c1[g]);
  }
}

// ---------------- Bt[col][k] = bf16(W_att_out[k][col]) ----------------
__global__ void k_bt(const float* __restrict__ W, ushort* __restrict__ Bt) {
  int t = threadIdx.x;
  int col = blockIdx.x * 2 + (t >> 7);
  int kg = t & 127;
  ushort u[8];
#pragma unroll
  for (int j = 0; j < 8; ++j) u[j] = f2bf(W[(long)(kg * 8 + j) * cH + col]);
  int4 o;
  o.x = (int)u[0] | ((int)u[1] << 16);
  o.y = (int)u[2] | ((int)u[3] << 16);
  o.z = (int)u[4] | ((int)u[5] << 16);
  o.w = (int)u[6] | ((int)u[7] << 16);
  *(int4*)(Bt + (long)col * 1024 + kg * 8) = o;
}

// ---------------- out = tanh(cat @ W_att_out + b) via MFMA bf16 ----------------
// grid (32 row-tiles, 8 col-tiles); block 256 (4 waves); tile 64x64, K=1024 (16 chunks)
__global__ void __launch_bounds__(256) k_out_mfma(
    const ushort* __restrict__ cat, const ushort* __restrict__ Bt,
    const float* __restrict__ bias, float* __restrict__ out) {
  __shared__ char lds[16384];
  int bn0 = blockIdx.x * 64, col0 = blockIdx.y * 64;
  int t = threadIdx.x;
  int w = t >> 6, lane = t & 63;
  f32x4 acc[4];
#pragma unroll
  for (int i = 0; i < 4; ++i) acc[i] = (f32x4){0.f, 0.f, 0.f, 0.f};
  int r = lane & 15, kg = lane >> 4;
  for (int kc = 0; kc < 16; ++kc) {
    int k0 = kc * 64;
#pragma unroll
    for (int p = 0; p < 2; ++p) {
      int i = t + p * 256;
      int row = i >> 3, ks = i & 7;
      float4 va = *(const float4*)(cat + (long)(bn0 + row) * 1024 + k0 + ks * 8);
      *(float4*)(lds + ((row * 128 + ks * 16) ^ ((row & 7) << 4))) = va;
      float4 vb = *(const float4*)(Bt + (long)(col0 + row) * 1024 + k0 + ks * 8);
      *(float4*)(lds + 8192 + ((row * 128 + ks * 16) ^ ((row & 7) << 4))) = vb;
    }
    __syncthreads();
#pragma unroll
    for (int s = 0; s < 2; ++s) {
      int arow = w * 16 + r;
      bf16x8 a = *(const bf16x8*)(lds + ((arow * 128 + s * 64 + kg * 16) ^ ((arow & 7) << 4)));
#pragma unroll
      for (int cf = 0; cf < 4; ++cf) {
        int bcol = cf * 16 + r;
        bf16x8 bb = *(const bf16x8*)(lds + 8192 +
                                     ((bcol * 128 + s * 64 + kg * 16) ^ ((bcol & 7) << 4)));
        acc[cf] = __builtin_amdgcn_mfma_f32_16x16x32_bf16(a, bb, acc[cf], 0, 0, 0);
      }
    }
    __syncthreads();
  }
  int rq = lane >> 4;
#pragma unroll
  for (int cf = 0; cf < 4; ++cf) {
    int col = col0 + cf * 16 + r;
    float bv = bias[col];
#pragma unroll
    for (int reg = 0; reg < 4; ++reg) {
      int row = bn0 + w * 16 + rq * 4 + reg;
      out[(long)row * cH + col] = tanhf(acc[cf][reg] + bv);
    }
  }
}

extern "C" void kernel_launch(void* const* d_in, const int* in_sizes, int n_in,
                              void* d_out, int out_size, void* d_ws, size_t ws_size,
                              hipStream_t stream) {
  const int* sents = (const int*)d_in[0];
  const int* titles = (const int*)d_in[1];
  const float* emb = (const float*)d_in[2];
  const float* Wt = (const float*)d_in[3];
  const float* bt = (const float*)d_in[4];
  const float* W_ih = (const float*)d_in[5];
  const float* W_hh = (const float*)d_in[6];
  const float* b_ih = (const float*)d_in[7];
  const float* b_hh = (const float*)d_in[8];
  const float* W_att_in = (const float*)d_in[9];
  const float* W_att_out = (const float*)d_in[10];
  const float* b_att_out = (const float*)d_in[11];
  float* out = (float*)d_out;

  float* ws = (float*)d_ws;
  float* x = ws;                                   // old x region: holds Wp (1.5 < 2.1 MB)
  uint4* Wp = (uint4*)x;
  float* tsum = x + (long)cBN * cD;                // B*D
  float* gi = tsum + (long)cB * cD;                // BN*3H f32 (live through scan)
  float* hse = gi + (long)cBN * cH3;               // B*65*H f32
  float* c = hse + (long)cB * cNP1 * cH;           // (f32 region kept; unused)
  ushort* xb = (ushort*)(c + (long)cBN * cH);      // 1 MB
  ushort* bti = xb + (long)cBN * cD;               // 0.75 MB
  ushort* bq = bti + (long)cH3 * cD;               // 0.5 MB
  // dead-gi aliases (after scan): q | catb | Btb | hsb  (11.4 < 12.6 MB)
  float* q = gi;
  ushort* catb = (ushort*)(gi + (long)cBN * cH);
  ushort* Btb = catb + (long)cBN * 1024;
  ushort* hsb = Btb + (long)cH * 1024;

  k_embed_x<<<cBN, 256, 0, stream>>>(sents, emb, xb);
  k_title<<<cB, 256, 0, stream>>>(titles, emb, tsum);
  k_h0<<<(cB * cH) / 256, 256, 0, stream>>>(tsum, Wt, bt, hse);
  k_bti<<<dim3(24, 4), 256, 0, stream>>>(W_ih, bti);
  k_bq<<<dim3(8, 8), 256, 0, stream>>>(W_att_in, bq);
  k_wpack<<<dim3(64, 6), 256, 0, stream>>>(W_hh, Wp);
  k_gi_mfma<<<dim3(32, 24), 256, 0, stream>>>(xb, bti, b_ih, gi);
  for (int step = 0; step < cN; ++step)
    k_gru_step<<<64, 256, 0, stream>>>(gi, Wp, b_hh, hse, step);
  k_hscast<<<cBN, 128, 0, stream>>>(hse, hsb, catb);
  k_q_mfma<<<dim3(32, 8), 256, 0, stream>>>(hsb, bq, q);
  k_attn2<<<dim3(cB, 16), 256, 0, stream>>>(q, hse, catb);
  k_bt<<<256, 256, 0, stream>>>(W_att_out, Btb);
  k_out_mfma<<<dim3(32, 8), 256, 0, stream>>>(catb, Btb, b_att_out, out);
}

// Round 23
// 439.039 us; speedup vs baseline: 2.1949x; 2.1949x over previous
//
#include <hip/hip_runtime.h>
#include <hip/hip_bf16.h>

constexpr int cB = 32, cN = 64, cL = 64, cT = 10, cD = 256, cH = 512, cH3 = 1536;
constexpr int cBN = cB * cN;   // 2048
constexpr int cNP1 = cN + 1;   // 65: hidden tape, slot 0 = h0, slot n+1 = hs[:,n,:]

typedef __bf16 bf16x8 __attribute__((ext_vector_type(8)));
typedef float f32x4 __attribute__((ext_vector_type(4)));
typedef _Float16 h2t __attribute__((ext_vector_type(2)));

__device__ __forceinline__ ushort f2bf(float f) {
  __hip_bfloat16 h = __float2bfloat16(f);
  return *reinterpret_cast<ushort*>(&h);
}

// pack two f32 -> two f16 in one uint (v_cvt_pkrtz_f16_f32)
__device__ __forceinline__ unsigned pkh2(float a, float b) {
  auto p = __builtin_amdgcn_cvt_pkrtz(a, b);   // __fp16 ext_vector(2)
  return __builtin_bit_cast(unsigned, p);
}

// f16-pair dot with f32 accumulator
__device__ __forceinline__ float fdot2u(unsigned w, unsigned h, float acc) {
#if __has_builtin(__builtin_amdgcn_fdot2)
  return __builtin_amdgcn_fdot2(__builtin_bit_cast(h2t, w),
                                __builtin_bit_cast(h2t, h), acc, false);
#else
  h2t a = __builtin_bit_cast(h2t, w), b = __builtin_bit_cast(h2t, h);
  return acc + (float)a[0] * (float)b[0] + (float)a[1] * (float)b[1];
#endif
}

// ---------------- xb[bn][d] = bf16( sum_l emb[sents[bn][l]][d] ) ----------------
__global__ void k_embed_x(const int* __restrict__ sents, const float* __restrict__ emb,
                          ushort* __restrict__ xb) {
  __shared__ int idx[cL];
  int bn = blockIdx.x, t = threadIdx.x;
  if (t < cL) idx[t] = sents[bn * cL + t];
  __syncthreads();
  float acc = 0.f;
#pragma unroll 8
  for (int l = 0; l < cL; ++l) acc += emb[(long)idx[l] * cD + t];
  xb[bn * cD + t] = f2bf(acc);
}

// ---------------- tsum[b][d] = sum_t emb[titles[b][0][t]][d] ----------------
__global__ void k_title(const int* __restrict__ titles, const float* __restrict__ emb,
                        float* __restrict__ tsum) {
  __shared__ int idx[cT];
  int b = blockIdx.x, t = threadIdx.x;
  if (t < cT) idx[t] = titles[b * cN * cT + t];
  __syncthreads();
  float acc = 0.f;
#pragma unroll
  for (int i = 0; i < cT; ++i) acc += emb[(long)idx[i] * cD + t];
  tsum[b * cD + t] = acc;
}

// ---------------- h0 = tsum @ Wt + bt -> hse slot 0 ----------------
__global__ void k_h0(const float* __restrict__ tsum, const float* __restrict__ Wt,
                     const float* __restrict__ bt, float* __restrict__ hse) {
  int i = blockIdx.x * blockDim.x + threadIdx.x;  // B*H
  int b = i >> 9, hh = i & (cH - 1);
  const float* ts = tsum + b * cD;
  float acc = bt[hh];
  for (int k = 0; k < cD; ++k) acc += ts[k] * Wt[(long)k * cH + hh];
  hse[(long)b * cNP1 * cH + hh] = acc;
}

// ---------------- W_ih -> transposed bf16: bti[col][k] ----------------
__global__ void k_bti(const float* __restrict__ W, ushort* __restrict__ Bt) {
  __shared__ float tile[64][65];
  int col0 = blockIdx.x * 64, k0 = blockIdx.y * 64;
  int t = threadIdx.x;
  for (int i = t; i < 4096; i += 256) {
    int kr = i >> 6, cc = i & 63;
    tile[kr][cc] = W[(long)(k0 + kr) * cH3 + col0 + cc];
  }
  __syncthreads();
  for (int i = t; i < 4096; i += 256) {
    int cc = i >> 6, kr = i & 63;
    Bt[(long)(col0 + cc) * cD + k0 + kr] = f2bf(tile[kr][cc]);
  }
}

// ---------------- W_att_in -> transposed bf16: bq[col][k] ----------------
__global__ void k_bq(const float* __restrict__ W, ushort* __restrict__ Bt) {
  __shared__ float tile[64][65];
  int col0 = blockIdx.x * 64, k0 = blockIdx.y * 64;
  int t = threadIdx.x;
  for (int i = t; i < 4096; i += 256) {
    int kr = i >> 6, cc = i & 63;
    tile[kr][cc] = W[(long)(k0 + kr) * cH + col0 + cc];
  }
  __syncthreads();
  for (int i = t; i < 4096; i += 256) {
    int cc = i >> 6, kr = i & 63;
    Bt[(long)(col0 + cc) * cH + k0 + kr] = f2bf(tile[kr][cc]);
  }
}

// ---------------- W_hh -> f16-pair packed: Wp[(g*64+k8)*512 + c] = 8 halves ----------------
// grid (64 k8, 6 cg); block 256
__global__ void k_wpack(const float* __restrict__ W, uint4* __restrict__ Wp) {
  int k8 = blockIdx.x, cg = blockIdx.y;
  int t = threadIdx.x;
  int cglob = cg * 256 + t;          // 0..1535
  int g = cglob >> 9, c = cglob & 511;
  float v[8];
#pragma unroll
  for (int j = 0; j < 8; ++j) v[j] = W[(long)(k8 * 8 + j) * cH3 + cglob];
  Wp[(g * 64 + k8) * 512 + c] = make_uint4(pkh2(v[0], v[1]), pkh2(v[2], v[3]),
                                           pkh2(v[4], v[5]), pkh2(v[6], v[7]));
}

// ---------------- GI = X @ W_ih + b_ih via MFMA ----------------
// grid (32 row-tiles, 24 col-tiles); block 256 (4 waves); tile 64x64, K=256 (4 chunks)
__global__ void __launch_bounds__(256) k_gi_mfma(
    const ushort* __restrict__ xb, const ushort* __restrict__ Bt,
    const float* __restrict__ b_ih, float* __restrict__ gi) {
  __shared__ char lds[16384];
  int bn0 = blockIdx.x * 64, col0 = blockIdx.y * 64;
  int t = threadIdx.x;
  int w = t >> 6, lane = t & 63;
  f32x4 acc[4];
#pragma unroll
  for (int i = 0; i < 4; ++i) acc[i] = (f32x4){0.f, 0.f, 0.f, 0.f};
  int r = lane & 15, kg = lane >> 4;
  for (int kc = 0; kc < 4; ++kc) {
    int k0 = kc * 64;
#pragma unroll
    for (int p = 0; p < 2; ++p) {
      int i = t + p * 256;
      int row = i >> 3, ks = i & 7;
      float4 va = *(const float4*)(xb + (long)(bn0 + row) * cD + k0 + ks * 8);
      *(float4*)(lds + ((row * 128 + ks * 16) ^ ((row & 7) << 4))) = va;
      float4 vb = *(const float4*)(Bt + (long)(col0 + row) * cD + k0 + ks * 8);
      *(float4*)(lds + 8192 + ((row * 128 + ks * 16) ^ ((row & 7) << 4))) = vb;
    }
    __syncthreads();
#pragma unroll
    for (int s = 0; s < 2; ++s) {
      int arow = w * 16 + r;
      bf16x8 a = *(const bf16x8*)(lds + ((arow * 128 + s * 64 + kg * 16) ^ ((arow & 7) << 4)));
#pragma unroll
      for (int cf = 0; cf < 4; ++cf) {
        int bcol = cf * 16 + r;
        bf16x8 bb = *(const bf16x8*)(lds + 8192 +
                                     ((bcol * 128 + s * 64 + kg * 16) ^ ((bcol & 7) << 4)));
        acc[cf] = __builtin_amdgcn_mfma_f32_16x16x32_bf16(a, bb, acc[cf], 0, 0, 0);
      }
    }
    __syncthreads();
  }
  int rq = lane >> 4;
#pragma unroll
  for (int cf = 0; cf < 4; ++cf) {
    int col = col0 + cf * 16 + r;
    float bv = b_ih[col];
#pragma unroll
    for (int reg = 0; reg < 4; ++reg) {
      int row = bn0 + w * 16 + rq * 4 + reg;
      gi[(long)row * cH3 + col] = acc[cf][reg] + bv;
    }
  }
}

// ---------------- one GRU step (v8: 256 thr, f16 dot2, kp=16; r18/r21-proven pattern) ----------------
// grid 256 = bg(8: 4 batches) x cg(32: 16 cols/gate); block 256
// t = kp(t>>4: 16 parts of 32 k) | b((t>>2)&3) | c4(t&3: 4-col quad)
__global__ void __launch_bounds__(256) k_gru_step(
    const float* __restrict__ gi, const uint4* __restrict__ Wp,
    const float* __restrict__ b_hh, float* __restrict__ hse, int step) {
  __shared__ float part[256][13];
  int cg = blockIdx.x & 31;
  int bg = blockIdx.x >> 5;
  int t = threadIdx.x;

  // epilogue operands prefetched at entry (t < 64: one lane per output)
  float ir = 0.f, iz = 0.f, in_ = 0.f, bhr = 0.f, bhz = 0.f, bhn = 0.f, hold = 0.f;
  int e_bl = (t >> 4) & 3, e_cl = t & 15;
  if (t < 64) {
    int bb = bg * 4 + e_bl;
    int hh = cg * 16 + e_cl;
    long girow = ((long)bb * cN + step) * cH3;
    ir = gi[girow + hh];
    iz = gi[girow + hh + cH];
    in_ = gi[girow + hh + 2 * cH];
    bhr = b_hh[hh];
    bhz = b_hh[hh + cH];
    bhn = b_hh[hh + 2 * cH];
    hold = hse[((long)bb * cNP1 + step) * cH + hh];
  }

  int c4 = t & 3, b = (t >> 2) & 3, kp = t >> 4;
  int col0 = cg * 16 + c4 * 4;
  const float* hrow = hse + ((long)(bg * 4 + b) * cNP1 + step) * cH;
  int k0 = kp * 32;
  // load 32 h values, pack to f16 pairs (4 uint4 = 4 k8-groups)
  uint4 hp[4];
#pragma unroll
  for (int i = 0; i < 4; ++i) {
    float4 v0 = *(const float4*)(hrow + k0 + i * 8);
    float4 v1 = *(const float4*)(hrow + k0 + i * 8 + 4);
    hp[i] = make_uint4(pkh2(v0.x, v0.y), pkh2(v0.z, v0.w),
                       pkh2(v1.x, v1.y), pkh2(v1.z, v1.w));
  }

  float ar[4] = {0, 0, 0, 0}, az[4] = {0, 0, 0, 0}, an[4] = {0, 0, 0, 0};
#pragma unroll
  for (int i = 0; i < 4; ++i) {
    int k8 = kp * 4 + i;
    uint4 h4 = hp[i];
#pragma unroll
    for (int j = 0; j < 4; ++j) {
      int col = col0 + j;
      uint4 wr = Wp[(0 * 64 + k8) * 512 + col];
      uint4 wz = Wp[(1 * 64 + k8) * 512 + col];
      uint4 wn = Wp[(2 * 64 + k8) * 512 + col];
      ar[j] = fdot2u(wr.x, h4.x, ar[j]); ar[j] = fdot2u(wr.y, h4.y, ar[j]);
      ar[j] = fdot2u(wr.z, h4.z, ar[j]); ar[j] = fdot2u(wr.w, h4.w, ar[j]);
      az[j] = fdot2u(wz.x, h4.x, az[j]); az[j] = fdot2u(wz.y, h4.y, az[j]);
      az[j] = fdot2u(wz.z, h4.z, az[j]); az[j] = fdot2u(wz.w, h4.w, az[j]);
      an[j] = fdot2u(wn.x, h4.x, an[j]); an[j] = fdot2u(wn.y, h4.y, an[j]);
      an[j] = fdot2u(wn.z, h4.z, an[j]); an[j] = fdot2u(wn.w, h4.w, an[j]);
    }
  }
#pragma unroll
  for (int j = 0; j < 4; ++j) {
    part[t][j] = ar[j];
    part[t][4 + j] = az[j];
    part[t][8 + j] = an[j];
  }
  __syncthreads();
  if (t < 64) {  // 64 outputs, each lane sums its 16 partials
    int c4f = e_cl >> 2, jf = e_cl & 3;
    float sr = 0.f, sz = 0.f, sn = 0.f;
#pragma unroll
    for (int p = 0; p < 16; ++p) {
      const float* pp = part[p * 16 + e_bl * 4 + c4f];
      sr += pp[jf];
      sz += pp[4 + jf];
      sn += pp[8 + jf];
    }
    int bb = bg * 4 + e_bl;
    int hh = cg * 16 + e_cl;
    float rr = 1.f / (1.f + __expf(-(ir + sr + bhr)));
    float zz = 1.f / (1.f + __expf(-(iz + sz + bhz)));
    float nn = tanhf(in_ + rr * (sn + bhn));
    hse[((long)bb * cNP1 + step + 1) * cH + hh] = (1.f - zz) * nn + zz * hold;
  }
}

// ---------------- hs -> bf16: hsb[bn][k]  AND catb upper half ----------------
__global__ void k_hscast(const float* __restrict__ hse, ushort* __restrict__ hsb,
                         ushort* __restrict__ catb) {
  int bn = blockIdx.x, t = threadIdx.x;  // 128 threads x float4
  int b = bn >> 6, n = bn & 63;
  float4 v = ((const float4*)(hse + ((long)b * cNP1 + 1 + n) * cH))[t];
  ushort4 o;
  o.x = f2bf(v.x); o.y = f2bf(v.y); o.z = f2bf(v.z); o.w = f2bf(v.w);
  *(ushort4*)(hsb + (long)bn * cH + t * 4) = o;
  *(ushort4*)(catb + (long)bn * 1024 + 512 + t * 4) = o;
}

// ---------------- q = hs @ W_att_in via MFMA ----------------
// grid (32 row-tiles, 8 col-tiles); block 256 (4 waves); tile 64x64, K=512 (8 chunks)
__global__ void __launch_bounds__(256) k_q_mfma(
    const ushort* __restrict__ hsb, const ushort* __restrict__ Bt,
    float* __restrict__ q) {
  __shared__ char lds[16384];
  int bn0 = blockIdx.x * 64, col0 = blockIdx.y * 64;
  int t = threadIdx.x;
  int w = t >> 6, lane = t & 63;
  f32x4 acc[4];
#pragma unroll
  for (int i = 0; i < 4; ++i) acc[i] = (f32x4){0.f, 0.f, 0.f, 0.f};
  int r = lane & 15, kg = lane >> 4;
  for (int kc = 0; kc < 8; ++kc) {
    int k0 = kc * 64;
#pragma unroll
    for (int p = 0; p < 2; ++p) {
      int i = t + p * 256;
      int row = i >> 3, ks = i & 7;
      float4 va = *(const float4*)(hsb + (long)(bn0 + row) * cH + k0 + ks * 8);
      *(float4*)(lds + ((row * 128 + ks * 16) ^ ((row & 7) << 4))) = va;
      float4 vb = *(const float4*)(Bt + (long)(col0 + row) * cH + k0 + ks * 8);
      *(float4*)(lds + 8192 + ((row * 128 + ks * 16) ^ ((row & 7) << 4))) = vb;
    }
    __syncthreads();
#pragma unroll
    for (int s = 0; s < 2; ++s) {
      int arow = w * 16 + r;
      bf16x8 a = *(const bf16x8*)(lds + ((arow * 128 + s * 64 + kg * 16) ^ ((arow & 7) << 4)));
#pragma unroll
      for (int cf = 0; cf < 4; ++cf) {
        int bcol = cf * 16 + r;
        bf16x8 bb = *(const bf16x8*)(lds + 8192 +
                                     ((bcol * 128 + s * 64 + kg * 16) ^ ((bcol & 7) << 4)));
        acc[cf] = __builtin_amdgcn_mfma_f32_16x16x32_bf16(a, bb, acc[cf], 0, 0, 0);
      }
    }
    __syncthreads();
  }
  int rq = lane >> 4;
#pragma unroll
  for (int cf = 0; cf < 4; ++cf) {
    int col = col0 + cf * 16 + r;
#pragma unroll
    for (int reg = 0; reg < 4; ++reg) {
      int row = bn0 + w * 16 + rq * 4 + reg;
      q[(long)row * cH + col] = acc[cf][reg];
    }
  }
}

// ---------------- causal attention v2: 4 queries/block, key early-exit ----------------
// grid (32 b, 16 qg); block 256. Writes catb lower half (bf16 context).
__global__ void k_attn2(const float* __restrict__ q, const float* __restrict__ hse,
                        ushort* __restrict__ catb) {
  __shared__ float qs[4][cH];       // 8 KB
  __shared__ float part[256][5];    // stride 5: conflict-free (gcd(5,32)=1)
  __shared__ float aw[4][cN];
  int b = blockIdx.x, qg = blockIdx.y;
  int n0 = qg * 4;
  int kmax = n0 + 3;
  int t = threadIdx.x;
  for (int i = t; i < 4 * 128; i += 256) {
    int g = i >> 7, j = i & 127;
    ((float4*)qs[g])[j] = ((const float4*)(q + (long)(b * 64 + n0 + g) * cH))[j];
  }
  __syncthreads();
  int k = t & 63, p = t >> 6;
  float s0 = 0.f, s1 = 0.f, s2 = 0.f, s3 = 0.f;
  if (k <= kmax) {
    const float* hrow = hse + ((long)b * cNP1 + 1 + k) * cH + p * 128;
    const float* q0 = &qs[0][p * 128];
    const float* q1 = &qs[1][p * 128];
    const float* q2 = &qs[2][p * 128];
    const float* q3 = &qs[3][p * 128];
#pragma unroll 4
    for (int j = 0; j < 128; ++j) {
      float hv = hrow[j];
      s0 += q0[j] * hv;
      s1 += q1[j] * hv;
      s2 += q2[j] * hv;
      s3 += q3[j] * hv;
    }
  }
  part[t][0] = s0; part[t][1] = s1; part[t][2] = s2; part[t][3] = s3;
  __syncthreads();
  if (t < 64) {
#pragma unroll
    for (int g = 0; g < 4; ++g) {
      float sc = part[t][g] + part[t + 64][g] + part[t + 128][g] + part[t + 192][g];
      if (t > n0 + g) sc = -1e30f;  // causal (ref's log(1e-45) -> exp underflow)
      float m = sc;
#pragma unroll
      for (int off = 32; off; off >>= 1) m = fmaxf(m, __shfl_xor(m, off));
      float e = __expf(sc - m);
      float sum = e;
#pragma unroll
      for (int off = 32; off; off >>= 1) sum += __shfl_xor(sum, off);
      aw[g][t] = e / sum;
    }
  }
  __syncthreads();
  float c0[4] = {0, 0, 0, 0}, c1[4] = {0, 0, 0, 0};
  for (int kk = 0; kk <= kmax; ++kk) {
    const float* hr = hse + ((long)b * cNP1 + 1 + kk) * cH;
    float h0 = hr[t], h1 = hr[t + 256];
#pragma unroll
    for (int g = 0; g < 4; ++g) {
      float a = aw[g][kk];
      c0[g] += a * h0;
      c1[g] += a * h1;
    }
  }
#pragma unroll
  for (int g = 0; g < 4; ++g) {
    long row = (long)(b * 64 + n0 + g) * 1024;
    catb[row + t] = f2bf(c0[g]);
    catb[row + t + 256] = f2bf(c1[g]);
  }
}

// ---------------- Bt[col][k] = bf16(W_att_out[k][col]) ----------------
__global__ void k_bt(const float* __restrict__ W, ushort* __restrict__ Bt) {
  int t = threadIdx.x;
  int col = blockIdx.x * 2 + (t >> 7);
  int kg = t & 127;
  ushort u[8];
#pragma unroll
  for (int j = 0; j < 8; ++j) u[j] = f2bf(W[(long)(kg * 8 + j) * cH + col]);
  int4 o;
  o.x = (int)u[0] | ((int)u[1] << 16);
  o.y = (int)u[2] | ((int)u[3] << 16);
  o.z = (int)u[4] | ((int)u[5] << 16);
  o.w = (int)u[6] | ((int)u[7] << 16);
  *(int4*)(Bt + (long)col * 1024 + kg * 8) = o;
}

// ---------------- out = tanh(cat @ W_att_out + b) via MFMA bf16 ----------------
// grid (32 row-tiles, 8 col-tiles); block 256 (4 waves); tile 64x64, K=1024 (16 chunks)
__global__ void __launch_bounds__(256) k_out_mfma(
    const ushort* __restrict__ cat, const ushort* __restrict__ Bt,
    const float* __restrict__ bias, float* __restrict__ out) {
  __shared__ char lds[16384];
  int bn0 = blockIdx.x * 64, col0 = blockIdx.y * 64;
  int t = threadIdx.x;
  int w = t >> 6, lane = t & 63;
  f32x4 acc[4];
#pragma unroll
  for (int i = 0; i < 4; ++i) acc[i] = (f32x4){0.f, 0.f, 0.f, 0.f};
  int r = lane & 15, kg = lane >> 4;
  for (int kc = 0; kc < 16; ++kc) {
    int k0 = kc * 64;
#pragma unroll
    for (int p = 0; p < 2; ++p) {
      int i = t + p * 256;
      int row = i >> 3, ks = i & 7;
      float4 va = *(const float4*)(cat + (long)(bn0 + row) * 1024 + k0 + ks * 8);
      *(float4*)(lds + ((row * 128 + ks * 16) ^ ((row & 7) << 4))) = va;
      float4 vb = *(const float4*)(Bt + (long)(col0 + row) * 1024 + k0 + ks * 8);
      *(float4*)(lds + 8192 + ((row * 128 + ks * 16) ^ ((row & 7) << 4))) = vb;
    }
    __syncthreads();
#pragma unroll
    for (int s = 0; s < 2; ++s) {
      int arow = w * 16 + r;
      bf16x8 a = *(const bf16x8*)(lds + ((arow * 128 + s * 64 + kg * 16) ^ ((arow & 7) << 4)));
#pragma unroll
      for (int cf = 0; cf < 4; ++cf) {
        int bcol = cf * 16 + r;
        bf16x8 bb = *(const bf16x8*)(lds + 8192 +
                                     ((bcol * 128 + s * 64 + kg * 16) ^ ((bcol & 7) << 4)));
        acc[cf] = __builtin_amdgcn_mfma_f32_16x16x32_bf16(a, bb, acc[cf], 0, 0, 0);
      }
    }
    __syncthreads();
  }
  int rq = lane >> 4;
#pragma unroll
  for (int cf = 0; cf < 4; ++cf) {
    int col = col0 + cf * 16 + r;
    float bv = bias[col];
#pragma unroll
    for (int reg = 0; reg < 4; ++reg) {
      int row = bn0 + w * 16 + rq * 4 + reg;
      out[(long)row * cH + col] = tanhf(acc[cf][reg] + bv);
    }
  }
}

extern "C" void kernel_launch(void* const* d_in, const int* in_sizes, int n_in,
                              void* d_out, int out_size, void* d_ws, size_t ws_size,
                              hipStream_t stream) {
  const int* sents = (const int*)d_in[0];
  const int* titles = (const int*)d_in[1];
  const float* emb = (const float*)d_in[2];
  const float* Wt = (const float*)d_in[3];
  const float* bt = (const float*)d_in[4];
  const float* W_ih = (const float*)d_in[5];
  const float* W_hh = (const float*)d_in[6];
  const float* b_ih = (const float*)d_in[7];
  const float* b_hh = (const float*)d_in[8];
  const float* W_att_in = (const float*)d_in[9];
  const float* W_att_out = (const float*)d_in[10];
  const float* b_att_out = (const float*)d_in[11];
  float* out = (float*)d_out;

  float* ws = (float*)d_ws;
  float* x = ws;                                   // old x region: holds Wp (1.5 < 2.1 MB)
  uint4* Wp = (uint4*)x;
  float* tsum = x + (long)cBN * cD;                // B*D
  float* gi = tsum + (long)cB * cD;                // BN*3H f32 (live through scan)
  float* hse = gi + (long)cBN * cH3;               // B*65*H f32
  float* c = hse + (long)cB * cNP1 * cH;           // (f32 region kept; unused)
  ushort* xb = (ushort*)(c + (long)cBN * cH);      // 1 MB
  ushort* bti = xb + (long)cBN * cD;               // 0.75 MB
  ushort* bq = bti + (long)cH3 * cD;               // 0.5 MB
  // dead-gi aliases (after scan): q | catb | Btb | hsb  (11.4 < 12.6 MB)
  float* q = gi;
  ushort* catb = (ushort*)(gi + (long)cBN * cH);
  ushort* Btb = catb + (long)cBN * 1024;
  ushort* hsb = Btb + (long)cH * 1024;

  k_embed_x<<<cBN, 256, 0, stream>>>(sents, emb, xb);
  k_title<<<cB, 256, 0, stream>>>(titles, emb, tsum);
  k_h0<<<(cB * cH) / 256, 256, 0, stream>>>(tsum, Wt, bt, hse);
  k_bti<<<dim3(24, 4), 256, 0, stream>>>(W_ih, bti);
  k_bq<<<dim3(8, 8), 256, 0, stream>>>(W_att_in, bq);
  k_wpack<<<dim3(64, 6), 256, 0, stream>>>(W_hh, Wp);
  k_gi_mfma<<<dim3(32, 24), 256, 0, stream>>>(xb, bti, b_ih, gi);
  for (int step = 0; step < cN; ++step)
    k_gru_step<<<256, 256, 0, stream>>>(gi, Wp, b_hh, hse, step);
  k_hscast<<<cBN, 128, 0, stream>>>(hse, hsb, catb);
  k_q_mfma<<<dim3(32, 8), 256, 0, stream>>>(hsb, bq, q);
  k_attn2<<<dim3(cB, 16), 256, 0, stream>>>(q, hse, catb);
  k_bt<<<256, 256, 0, stream>>>(W_att_out, Btb);
  k_out_mfma<<<dim3(32, 8), 256, 0, stream>>>(catb, Btb, b_att_out, out);
}